// Round 12
// baseline (382.733 us; speedup 1.0000x reference)
//
#include <hip/hip_runtime.h>
#include <stdint.h>

#define M_DIM 8192
#define N_DIM 8192
#define K_DIM 1024

typedef int int4v __attribute__((ext_vector_type(4)));

// ---- async global->LDS, 16B per lane ----
__device__ __forceinline__ void gload16(const char* g, char* l) {
    __builtin_amdgcn_global_load_lds(
        (__attribute__((address_space(1))) void*)(void*)const_cast<char*>(g),
        (__attribute__((address_space(3))) void*)l,
        16, 0, 0);
}

__device__ __forceinline__ int sat8(int v) {
    v = v > 127 ? 127 : v;
    v = v < -128 ? -128 : v;
    return v;
}

// ---- fused pack into TILE-MAJOR layout, T2 swizzle baked at store time ----
// Layout: [blk128][K64-slice(16)][row(128)][64B], 128KB per 128-row block.
// Stored 16B-chunk sc of (row, slice) holds logical chunk sc^((row>>1)&3).
// => GEMM staging reads are fully linear/contiguous (1KB per wave-instr).
__global__ __launch_bounds__(256) void pack_ab_kernel(const int* __restrict__ a,
                                                      const int* __restrict__ b,
                                                      char* __restrict__ outA,
                                                      char* __restrict__ outB) {
    __shared__ char tile[64][68];               // used by B-blocks only
    const int t = threadIdx.x;
    if (blockIdx.x < 8192) {
        // pack a: block bx handles row m=bx (1024 int32 -> 1024 int8)
        const int m   = blockIdx.x;
        const int row = m & 127;
        const int xr  = (row >> 1) & 3;          // baked swizzle constant
        const int4 v  = ((const int4*)a)[m * 256 + t];
        const int pk  = (v.x & 0xff) | ((v.y & 0xff) << 8) |
                        ((v.z & 0xff) << 16) | ((v.w & 0xff) << 24);
        const int k     = t * 4;
        const int slice = k >> 6;                // t>>4
        const int sc    = ((k >> 4) & 3) ^ xr;
        *(int*)&outA[(size_t)(m >> 7) * 131072 + slice * 8192 + row * 64 +
                     sc * 16 + (k & 15)] = pk;
        return;
    }
    // pack b: int32 [K][N] -> int8 tile-major [N-blk][K64][n-row][64B] (transpose)
    const int bx = blockIdx.x - 8192;           // 0..2047
    const int n0 = (bx & 127) * 64;
    const int k0 = (bx >> 7) * 64;
    const int tr  = t >> 4;                     // 0..15
    const int tc4 = (t & 15) << 2;              // 0,4,..,60
#pragma unroll
    for (int j = 0; j < 4; ++j) {
        int row = tr + j * 16;                  // k within tile
        int4 v = *(const int4*)&b[(size_t)(k0 + row) * N_DIM + n0 + tc4];
        tile[row][tc4 + 0] = (char)v.x;
        tile[row][tc4 + 1] = (char)v.y;
        tile[row][tc4 + 2] = (char)v.z;
        tile[row][tc4 + 3] = (char)v.w;
    }
    __syncthreads();
    const int slice = k0 >> 6;
#pragma unroll
    for (int j = 0; j < 4; ++j) {
        int n = tr + j * 16;                    // n within tile
        int pk = (tile[tc4 + 0][n] & 0xff) |
                 ((tile[tc4 + 1][n] & 0xff) << 8) |
                 ((tile[tc4 + 2][n] & 0xff) << 16) |
                 ((tile[tc4 + 3][n] & 0xff) << 24);
        const int ng  = n0 + n;
        const int row = ng & 127;
        const int sc  = (tc4 >> 4) ^ ((row >> 1) & 3);
        *(int*)&outB[(size_t)(ng >> 7) * 131072 + slice * 8192 + row * 64 +
                     sc * 16 + (tc4 & 15)] = pk;
    }
}

// ---- GEMM: 128x128 tile, WAVE-PRIVATE staging, ZERO barriers ----
// R11 post-mortem: the full 8-phase recipe nulled -> falsified at K=1024.
// Remaining untried mechanism (R7: all pipes <=26%, waves ganged; R9: load
// path is the one sensitive resource): the barriers themselves. Every prior
// variant gangs all waves into lockstep 2x per K-step, so each wave eats the
// gang's worst-case stage latency, and counted vmcnt can't help because the
// s_barrier re-serializes immediately (R3/R11 nulls).
// This kernel has NO s_barrier anywhere: each wave stages its OWN 64-row
// A/B halves into a private 16KB LDS region (A dbuf 2x4KB + B dbuf 2x4KB),
// tile-major source -> every gload is a linear 1KB burst (R9 scatter tax
// avoided). Self-sync via per-wave counted vmcnt(8): 2-slice ring, the wait
// for slice kt was issued 2 compute phases (~600cy) earlier >> L2 latency.
// Cost: 2x staging duplication (2GiB via L2 ~ 60us aggregate, overlapped)
// and 64KB LDS -> 2 blocks/CU; waves run fully desynced.
// Tail: stages clamp to slice 15 = same-bytes rewrite, benign. Per-wave
// vmcnt(0) before the epilogue reuses the wave's own region (still no
// barrier; regions are wave-private). Math/swizzle/epilogue/XCD map = R6.
__global__ __launch_bounds__(256) void gemm_i8_kernel(const char* __restrict__ A8,
                                                      const char* __restrict__ B8,
                                                      int* __restrict__ C) {
    __shared__ __align__(16) char smem[4][16384];   // per-wave private 16KB

    const int t    = threadIdx.x;
    // XCD-banded, bm-fast mapping (bijective over 4096 = 8 xcd x 8 band x 64 bn)
    const int xcd  = blockIdx.x & 7;
    const int j    = blockIdx.x >> 3;
    const int bm   = (xcd << 3) | (j & 7);
    const int bn   = j >> 3;
    const int lane = t & 63;
    const int wave = t >> 6;
    const int wm   = wave >> 1;                  // 2x2 wave grid, 64x64 per wave
    const int wn   = wave & 1;
    const int quad = lane >> 4;
    const int l16  = lane & 15;
    const int lb   = lane * 16;

    // wave's private staging: A bufs [0,8K), B bufs [8K,16K)
    char* myA = &smem[wave][0];
    char* myB = &smem[wave][8192];

    // wave's global sources: 4KB contiguous per K64-slice (tile-major layout)
    const char* aW = A8 + (size_t)bm * 131072 + wm * 4096;   // + slice*8192
    const char* bW = B8 + (size_t)bn * 131072 + wn * 4096;

    // swizzled read chunk (per-lane constant): stored sc = logical^((row>>1)&3);
    // wave-half base rows are multiples of 8 -> (row>>1)&3 == (l16>>1)&3.
    const int laneByte = ((quad ^ ((l16 >> 1) & 3)) << 4);

    int4v acc[4][4] = {};

#define STG(SL, BUF) do {                                                     \
    const char* as_ = aW + (SL) * 8192;                                       \
    const char* bs_ = bW + (SL) * 8192;                                       \
    char* la_ = myA + (BUF) * 4096;                                           \
    char* lb_ = myB + (BUF) * 4096;                                           \
    gload16(as_ + lb,        la_ + lb);                                       \
    gload16(as_ + 1024 + lb, la_ + 1024 + lb);                                \
    gload16(as_ + 2048 + lb, la_ + 2048 + lb);                                \
    gload16(as_ + 3072 + lb, la_ + 3072 + lb);                                \
    gload16(bs_ + lb,        lb_ + lb);                                       \
    gload16(bs_ + 1024 + lb, lb_ + 1024 + lb);                                \
    gload16(bs_ + 2048 + lb, lb_ + 2048 + lb);                                \
    gload16(bs_ + 3072 + lb, lb_ + 3072 + lb);                                \
} while (0)

    // prologue: slices 0,1 in flight (16 loads outstanding)
    STG(0, 0);
    STG(1, 1);

#pragma unroll 2
    for (int kt = 0; kt < 16; ++kt) {
        const int buf = kt & 1;
        // slice kt resident (retires its 8 loads; keeps next slice in flight)
        asm volatile("s_waitcnt vmcnt(8)" ::: "memory");
        __builtin_amdgcn_sched_barrier(0);

        int4v af[4], bf[4];
#pragma unroll
        for (int mi = 0; mi < 4; ++mi)
            af[mi] = *(const int4v*)
                &myA[buf * 4096 + (mi * 16 + l16) * 64 + laneByte];
#pragma unroll
        for (int ni = 0; ni < 4; ++ni)
            bf[ni] = *(const int4v*)
                &myB[buf * 4096 + (ni * 16 + l16) * 64 + laneByte];

        // fragments must be in regs before the DMA overwrites this buffer
        asm volatile("s_waitcnt lgkmcnt(0)" ::: "memory");
        __builtin_amdgcn_sched_barrier(0);

        // stage slice kt+2 into this buffer (tail clamps to 15: same-bytes
        // rewrite of a buffer whose data is already consumed -> benign)
        STG((kt + 2 < 16) ? kt + 2 : 15, buf);

        __builtin_amdgcn_s_setprio(1);
#pragma unroll
        for (int mi = 0; mi < 4; ++mi)
#pragma unroll
            for (int ni = 0; ni < 4; ++ni)
                acc[mi][ni] = __builtin_amdgcn_mfma_i32_16x16x64_i8(
                    af[mi], bf[ni], acc[mi][ni], 0, 0, 0);
        __builtin_amdgcn_s_setprio(0);
    }
#undef STG

    // own DMA writes drained before repurposing own region (no barrier:
    // the epilogue region below is inside this wave's private 16KB)
    asm volatile("s_waitcnt vmcnt(0)" ::: "memory");

    // epilogue (verified R8): acc (col=l16, row=4*quad+reg) -> wave-private
    // LDS transpose region (32 rows x 68-int padded) -> dwordx4 stores.
    int* lw = (int*)&smem[wave][0];              // 8704B used of 16KB
    const int mW = bm * 128 + wm * 64;
    const int nW = bn * 128 + wn * 64;
#pragma unroll
    for (int rnd = 0; rnd < 2; ++rnd) {
#pragma unroll
        for (int mh = 0; mh < 2; ++mh) {         // mi = rnd*2 + mh
            const int mi = rnd * 2 + mh;
#pragma unroll
            for (int ni = 0; ni < 4; ++ni)
#pragma unroll
                for (int r = 0; r < 4; ++r)
                    lw[(mh * 16 + quad * 4 + r) * 68 + ni * 16 + l16] =
                        sat8(acc[mi][ni][r]);
        }
        // same-wave DS ordering: compiler inserts lgkmcnt before dependent reads
#pragma unroll
        for (int rr = 0; rr < 8; ++rr) {
            const int R = rr * 4 + quad;         // local row 0..31
            const int4v v = *(const int4v*)&lw[R * 68 + l16 * 4];
            *(int4v*)&C[(size_t)(mW + rnd * 32 + R) * N_DIM + nW + l16 * 4] = v;
        }
        // round 2 writes ordered after round 1 reads by in-order per-wave DS pipe
    }
}

// ---- fallback (only if ws_size < 16MB): direct int32 GEMM, slow but correct ----
__global__ __launch_bounds__(256) void gemm_naive_kernel(const int* __restrict__ a,
                                                         const int* __restrict__ b,
                                                         int* __restrict__ C) {
    const int col = blockIdx.x * 256 + threadIdx.x;
    const int row = blockIdx.y;
    int acc = 0;
    for (int k = 0; k < K_DIM; ++k)
        acc += a[(size_t)row * K_DIM + k] * b[(size_t)k * N_DIM + col];
    C[(size_t)row * N_DIM + col] = sat8(acc);
}

extern "C" void kernel_launch(void* const* d_in, const int* in_sizes, int n_in,
                              void* d_out, int out_size, void* d_ws, size_t ws_size,
                              hipStream_t stream) {
    const int* a = (const int*)d_in[0];
    const int* b = (const int*)d_in[1];
    // alpha_row (d_in[2]) / alpha_col (d_in[3]) are unused in this variant.
    int* out = (int*)d_out;

    const size_t needed = 2 * (size_t)M_DIM * K_DIM;   // 16 MB packed operands
    if (ws_size < needed) {
        gemm_naive_kernel<<<dim3(N_DIM / 256, M_DIM), 256, 0, stream>>>(a, b, out);
        return;
    }

    char* A8 = (char*)d_ws;                          // 8 MB
    char* B8 = A8 + (size_t)M_DIM * K_DIM;           // 8 MB

    pack_ab_kernel<<<8192 + 2048, 256, 0, stream>>>(a, b, A8, B8);
    gemm_i8_kernel<<<4096, 256, 0, stream>>>(A8, B8, out);
}

// Round 13
// 366.299 us; speedup vs baseline: 1.0449x; 1.0449x over previous
//
#include <hip/hip_runtime.h>
#include <stdint.h>

#define M_DIM 8192
#define N_DIM 8192
#define K_DIM 1024
#define BK    128

typedef int int4v __attribute__((ext_vector_type(4)));

// ---- async global->LDS, 16B per lane ----
__device__ __forceinline__ void gload16(const char* g, char* l) {
    __builtin_amdgcn_global_load_lds(
        (__attribute__((address_space(1))) void*)(void*)const_cast<char*>(g),
        (__attribute__((address_space(3))) void*)l,
        16, 0, 0);
}

__device__ __forceinline__ int sat8(int v) {
    v = v > 127 ? 127 : v;
    v = v < -128 ? -128 : v;
    return v;
}

// ---- fused pack: blocks [0,8192) pack A; blocks [8192,10240) transpose-pack B ----
__global__ __launch_bounds__(256) void pack_ab_kernel(const int* __restrict__ a,
                                                      const int* __restrict__ b,
                                                      int* __restrict__ outA,
                                                      char* __restrict__ outB) {
    __shared__ char tile[64][68];               // used by B-blocks only
    const int t = threadIdx.x;
    if (blockIdx.x < 8192) {
        // pack a: int32 [M][K] -> int8 [M][K], 4 elems/thread, coalesced
        int i = blockIdx.x * 256 + t;
        int4 v = ((const int4*)a)[i];
        outA[i] = (v.x & 0xff) | ((v.y & 0xff) << 8) |
                  ((v.z & 0xff) << 16) | ((v.w & 0xff) << 24);
        return;
    }
    // pack b: int32 [K][N] -> int8 [N][K] (transpose via LDS tile)
    const int bx = blockIdx.x - 8192;           // 0..2047
    const int n0 = (bx & 127) * 64;
    const int k0 = (bx >> 7) * 64;
    const int tr  = t >> 4;                     // 0..15
    const int tc4 = (t & 15) << 2;              // 0,4,..,60
#pragma unroll
    for (int j = 0; j < 4; ++j) {
        int row = tr + j * 16;                  // k within tile
        int4 v = *(const int4*)&b[(size_t)(k0 + row) * N_DIM + n0 + tc4];
        tile[row][tc4 + 0] = (char)v.x;
        tile[row][tc4 + 1] = (char)v.y;
        tile[row][tc4 + 2] = (char)v.z;
        tile[row][tc4 + 3] = (char)v.w;
    }
    __syncthreads();
#pragma unroll
    for (int j = 0; j < 4; ++j) {
        int n = tr + j * 16;                    // n within tile
        int pk = (tile[tc4 + 0][n] & 0xff) |
                 ((tile[tc4 + 1][n] & 0xff) << 8) |
                 ((tile[tc4 + 2][n] & 0xff) << 16) |
                 ((tile[tc4 + 3][n] & 0xff) << 24);
        *(int*)&outB[(size_t)(n0 + n) * K_DIM + k0 + tc4] = pk;
    }
}

// ---- GEMM: 128x128 tile, BK=128, 4 waves — REVERT TO MEASURED BEST (R6) ----
// Session ledger (R0-R12): nine mechanism classes tried and falsified — LDS
// conflicts (R2), counted-vmcnt pipelines (R3/R11), occupancy + MFMA shape
// (R4), store vectorization (R5), XCD/L2 mapping (R6), 256^2 tiles (R8),
// direct-to-reg operands (R9, -115us: proved scatter/load-issue is the one
// sensitive pipe), tile-major linear staging (R10), barrier-free wave-private
// staging (R12, -19us). Direct measurement (R7 double-rep): gemm ~135us,
// MfmaUtil 20.6%, VALU 9.6%, Occupancy ~11%, no pipe >26% — consistent with
// a non-overlapping sum of phase costs (MFMA 35 + L2 31 + LDS 34 + C 41 ~
// 141us). No structural lever induced overlap. This file restores the best
// harness-verified variant (363.095us): R2 K-loop core + T2 swizzle,
// XCD-banded bm-fast block mapping, LDS-transposed dwordx4 epilogue.
__global__ __launch_bounds__(256) void gemm_i8_kernel(const char* __restrict__ A8,
                                                      const char* __restrict__ B8,
                                                      int* __restrict__ C) {
    // K-loop view: As = smem[0:16K), Bs = smem[16K:32K)  (2 x [k64-half][row][64B])
    // epilogue view: 4 waves x 32x68-int regions = 34816 B
    __shared__ __align__(16) char smem[4 * 8704];
    char* As = smem;
    char* Bs = smem + 16384;

    const int t    = threadIdx.x;
    // XCD-banded, bm-fast mapping (bijective over 4096 = 8 xcd x 8 band x 64 bn)
    const int xcd  = blockIdx.x & 7;
    const int j    = blockIdx.x >> 3;
    const int bm   = (xcd << 3) | (j & 7);
    const int bn   = j >> 3;
    const int lane = t & 63;
    const int wave = t >> 6;
    const int wm   = wave >> 1;                  // 2x2 wave grid, 64x64 per wave
    const int wn   = wave & 1;
    const int quad = lane >> 4;
    const int l16  = lane & 15;

    const size_t aBase = (size_t)(bm * 128) * K_DIM;
    const size_t bBase = (size_t)(bn * 128) * K_DIM;

    // staging: 4 slots/operand/thread, 16 B each
    const int sr = t >> 2;                       // row within 64-row half
    // T2 swizzle (rule 21): source chunk (t&3)^((t>>3)&3), LDS dest linear
    const int swzc = (((t & 3) ^ ((t >> 3) & 3)) << 4);
    // swizzled read chunk byte offset (per-lane constant)
    const int laneByte = ((quad ^ ((l16 >> 1) & 3)) << 4);

    int4v acc[4][4] = {};

    for (int kt = 0; kt < K_DIM / BK; ++kt) {
        const int kOff = kt * BK;
#pragma unroll
        for (int s = 0; s < 4; ++s) {
            const int p = s >> 1;                // K64-half
            const int rr = ((s & 1) << 6) + sr;  // tile row
            const int f = s * 4096 + t * 16;     // LDS flat offset (linear dest)
            gload16(A8 + aBase + (size_t)rr * K_DIM + kOff + p * 64 + swzc, As + f);
            gload16(B8 + bBase + (size_t)rr * K_DIM + kOff + p * 64 + swzc, Bs + f);
        }
        __syncthreads();   // drains vmcnt -> staged data visible

#pragma unroll
        for (int h = 0; h < 2; ++h) {            // two K64-halves per stage
            int4v af[4], bf[4];
#pragma unroll
            for (int mi = 0; mi < 4; ++mi)
                af[mi] = *(const int4v*)
                    &As[h * 8192 + (wm * 64 + mi * 16 + l16) * 64 + laneByte];
#pragma unroll
            for (int ni = 0; ni < 4; ++ni)
                bf[ni] = *(const int4v*)
                    &Bs[h * 8192 + (wn * 64 + ni * 16 + l16) * 64 + laneByte];

#pragma unroll
            for (int mi = 0; mi < 4; ++mi)
#pragma unroll
                for (int ni = 0; ni < 4; ++ni)
                    acc[mi][ni] = __builtin_amdgcn_mfma_i32_16x16x64_i8(
                        af[mi], bf[ni], acc[mi][ni], 0, 0, 0);
        }

        __syncthreads();   // LDS reads done before next stage overwrites
    }
    // after final barrier no wave touches As/Bs for the K-loop again; LDS is
    // repurposed per-wave (disjoint regions, no further barrier needed).

    // epilogue: acc (C/D layout: col=l16, row=4*quad+reg) -> per-wave LDS
    // transpose region (32 rows x 68-int padded stride) -> dwordx4 stores.
    int* lw = (int*)(smem + wave * 8704);        // 32*68 ints = 8704 B
    const int mW = bm * 128 + wm * 64;
    const int nW = bn * 128 + wn * 64;
#pragma unroll
    for (int rnd = 0; rnd < 2; ++rnd) {
#pragma unroll
        for (int mh = 0; mh < 2; ++mh) {         // mi = rnd*2 + mh
            const int mi = rnd * 2 + mh;
#pragma unroll
            for (int ni = 0; ni < 4; ++ni)
#pragma unroll
                for (int r = 0; r < 4; ++r)
                    lw[(mh * 16 + quad * 4 + r) * 68 + ni * 16 + l16] =
                        sat8(acc[mi][ni][r]);
        }
        // same-wave DS ordering: compiler inserts lgkmcnt before dependent reads
#pragma unroll
        for (int rr = 0; rr < 8; ++rr) {
            const int R = rr * 4 + quad;         // local row 0..31
            const int4v v = *(const int4v*)&lw[R * 68 + l16 * 4];
            *(int4v*)&C[(size_t)(mW + rnd * 32 + R) * N_DIM + nW + l16 * 4] = v;
        }
        // round 2 writes ordered after round 1 reads by in-order per-wave DS pipe
    }
}

// ---- fallback (only if ws_size < 16MB): direct int32 GEMM, slow but correct ----
__global__ __launch_bounds__(256) void gemm_naive_kernel(const int* __restrict__ a,
                                                         const int* __restrict__ b,
                                                         int* __restrict__ C) {
    const int col = blockIdx.x * 256 + threadIdx.x;
    const int row = blockIdx.y;
    int acc = 0;
    for (int k = 0; k < K_DIM; ++k)
        acc += a[(size_t)row * K_DIM + k] * b[(size_t)k * N_DIM + col];
    C[(size_t)row * N_DIM + col] = sat8(acc);
}

extern "C" void kernel_launch(void* const* d_in, const int* in_sizes, int n_in,
                              void* d_out, int out_size, void* d_ws, size_t ws_size,
                              hipStream_t stream) {
    const int* a = (const int*)d_in[0];
    const int* b = (const int*)d_in[1];
    // alpha_row (d_in[2]) / alpha_col (d_in[3]) are unused in this variant.
    int* out = (int*)d_out;

    const size_t needed = 2 * (size_t)M_DIM * K_DIM;   // 16 MB packed operands
    if (ws_size < needed) {
        gemm_naive_kernel<<<dim3(N_DIM / 256, M_DIM), 256, 0, stream>>>(a, b, out);
        return;
    }

    char* A8 = (char*)d_ws;                          // 8 MB
    char* B8 = A8 + (size_t)M_DIM * K_DIM;           // 8 MB

    pack_ab_kernel<<<8192 + 2048, 256, 0, stream>>>(a, b, (int*)A8, B8);
    gemm_i8_kernel<<<4096, 256, 0, stream>>>(A8, B8, out);
}